// Round 3
// baseline (233.230 us; speedup 1.0000x reference)
//
#include <hip/hip_runtime.h>
#include <math.h>

typedef unsigned short u16;
typedef unsigned int u32;
typedef __bf16 bfrag8 __attribute__((ext_vector_type(8)));
typedef float f32x4 __attribute__((ext_vector_type(4)));

#define B_ 2
#define T_ 2048
#define H_ 16
#define D_ 64
#define C_ 1024
#define NQKV_ 3072

#define MFMA_BF16(a, b, c) __builtin_amdgcn_mfma_f32_16x16x32_bf16((a), (b), (c), 0, 0, 0)

__device__ __forceinline__ u16 f2bf(float f) {
  u32 u = __builtin_bit_cast(u32, f);
  u += 0x7fffu + ((u >> 16) & 1u);  // RNE
  return (u16)(u >> 16);
}

// async global->LDS, 16B/lane; lds dest = wave-uniform base + lane*16
__device__ __forceinline__ void load_lds16(const u16* gp, u16* lp) {
  __builtin_amdgcn_global_load_lds(
      (const __attribute__((address_space(1))) u32*)(const void*)gp,
      (__attribute__((address_space(3))) u32*)(void*)lp, 16, 0, 0);
}
__device__ __forceinline__ void load_lds16f(const float* gp, float* lp) {
  __builtin_amdgcn_global_load_lds(
      (const __attribute__((address_space(1))) u32*)(const void*)gp,
      (__attribute__((address_space(3))) u32*)(void*)lp, 16, 0, 0);
}

// -------- transpose+convert weight: src f32 [K][N] -> dst bf16 [N][K] --------
__global__ __launch_bounds__(256) void transpose_w(const float* __restrict__ src,
                                                   u16* __restrict__ dst, int K, int N) {
  __shared__ u16 tile[64][65];
  int bx = blockIdx.x * 64;  // over N
  int by = blockIdx.y * 64;  // over K
  for (int idx = threadIdx.x; idx < 4096; idx += 256) {
    int r = idx >> 6, c = idx & 63;
    tile[r][c] = f2bf(src[(size_t)(by + r) * N + bx + c]);
  }
  __syncthreads();
  for (int idx = threadIdx.x; idx < 4096; idx += 256) {
    int r = idx >> 6, c = idx & 63;
    dst[(size_t)(bx + r) * K + by + c] = tile[c][r];
  }
}

// -------- GEMM 1: qkv = X(4096x1024 f32, converted in-kernel) @ WT(3072x1024)bf16,
// RoPE(+q*1/8) epilogue. 128x128 tile, BK=32, dbuf LDS, single barrier per K-iter
// (proven round-0 structure). New vs round-0:
//  * A staged as f32 via global_load_lds (chunk-XOR swizzled rows: LDS[r][c] holds
//    global 16B-chunk c^(r&7); read side applies same involution) and converted
//    f32->bf16 in-register at fragment build -> convert_x kernel deleted.
//  * XCD-bijective row-chunk blockIdx swizzle (768=8*96): each XCD owns 4 contiguous
//    M-rows -> A panels L2-resident (staging-BW relief for the doubled f32 A bytes).
__global__ __launch_bounds__(256) void gemm_qkv_rope(const float* __restrict__ Xf,
                                                     const u16* __restrict__ WT,
                                                     u16* __restrict__ qb,
                                                     u16* __restrict__ kb,
                                                     u16* __restrict__ vb) {
  const int K = C_;
  __shared__ __align__(16) float Asf[2][128 * 32];  // 32 KB
  __shared__ __align__(16) u16 Bs[2][128 * 32];     // 16 KB
  int tid = threadIdx.x;
  int lane = tid & 63, wave = tid >> 6;
  int quad = lane >> 4, lr = lane & 15;
  // bijective XCD row-chunk swizzle: grid (24,32), 768 blocks, 96/XCD = 4 M-rows x 24
  int id = blockIdx.x + blockIdx.y * 24;
  int nid = (id & 7) * 96 + (id >> 3);
  int m0 = (nid / 24) * 128, n0 = (nid % 24) * 128;
  int wrow = (wave >> 1) * 64, wcol = (wave & 1) * 64;
  int r0 = wave * 32;
  // B staging (bf16, linear): 16 rows x 32 cols per load
  int srowB = lane >> 2, skcB = (lane & 3) * 8;
  // A staging (f32, swizzled): 8 rows x 32 cols per load; source chunk = dest^row
  int srowA = lane >> 3;
  int schA = (lane & 7) ^ srowA;

  f32x4 zero = {0.f, 0.f, 0.f, 0.f};
  f32x4 acc[4][4];
#pragma unroll
  for (int i = 0; i < 4; i++)
#pragma unroll
    for (int j = 0; j < 4; j++) acc[i][j] = zero;

  const float* gaF = Xf + (size_t)(m0 + r0 + srowA) * K + schA * 4;
  const u16* gb0 = WT + (size_t)(n0 + r0 + srowB) * K + skcB;
  const u16* gb1 = WT + (size_t)(n0 + r0 + 16 + srowB) * K + skcB;

  load_lds16f(gaF, &Asf[0][r0 * 32]);
  load_lds16f(gaF + (size_t)8 * K, &Asf[0][(r0 + 8) * 32]);
  load_lds16f(gaF + (size_t)16 * K, &Asf[0][(r0 + 16) * 32]);
  load_lds16f(gaF + (size_t)24 * K, &Asf[0][(r0 + 24) * 32]);
  load_lds16(gb0, &Bs[0][r0 * 32]);
  load_lds16(gb1, &Bs[0][(r0 + 16) * 32]);

  // read-side swizzled f32-chunk offsets (f32 units): logical chunks 2q, 2q+1
  int ca0 = ((quad * 2) ^ (lr & 7)) * 4;
  int ca1 = ((quad * 2 + 1) ^ (lr & 7)) * 4;

  int buf = 0;
  for (int k0 = 0; k0 < K; k0 += 32) {
    __syncthreads();
    if (k0 + 32 < K) {
      load_lds16f(gaF + k0 + 32, &Asf[buf ^ 1][r0 * 32]);
      load_lds16f(gaF + (size_t)8 * K + k0 + 32, &Asf[buf ^ 1][(r0 + 8) * 32]);
      load_lds16f(gaF + (size_t)16 * K + k0 + 32, &Asf[buf ^ 1][(r0 + 16) * 32]);
      load_lds16f(gaF + (size_t)24 * K + k0 + 32, &Asf[buf ^ 1][(r0 + 24) * 32]);
      load_lds16(gb0 + k0 + 32, &Bs[buf ^ 1][r0 * 32]);
      load_lds16(gb1 + k0 + 32, &Bs[buf ^ 1][(r0 + 16) * 32]);
    }
    bfrag8 af[4], bfr[4];
#pragma unroll
    for (int i = 0; i < 4; i++) {
      const float* ar = &Asf[buf][(wrow + i * 16 + lr) * 32];
      float4 a0 = *(const float4*)(ar + ca0);  // logical cols quad*8..+3
      float4 a1 = *(const float4*)(ar + ca1);  // logical cols quad*8+4..+7
      bfrag8 f;
      f[0] = (__bf16)a0.x; f[1] = (__bf16)a0.y; f[2] = (__bf16)a0.z; f[3] = (__bf16)a0.w;
      f[4] = (__bf16)a1.x; f[5] = (__bf16)a1.y; f[6] = (__bf16)a1.z; f[7] = (__bf16)a1.w;
      af[i] = f;
    }
#pragma unroll
    for (int j = 0; j < 4; j++)
      bfr[j] = *(const bfrag8*)&Bs[buf][(wcol + j * 16 + lr) * 32 + quad * 8];
#pragma unroll
    for (int i = 0; i < 4; i++)
#pragma unroll
      for (int j = 0; j < 4; j++) acc[i][j] = MFMA_BF16(af[i], bfr[j], acc[i][j]);
    buf ^= 1;
  }

  int colbase = n0 + wcol;
  int which = colbase >> 10;  // 0=q 1=k 2=v
  int h = (colbase & 1023) >> 6;
  u16* dst = which == 0 ? qb : (which == 1 ? kb : vb);
  float sc0 = (which == 0) ? 0.125f : 1.0f;
  float fr0 = __expf(-0.28782313662425574f * (float)lr);        // ln(10000)/32
  float fr1 = __expf(-0.28782313662425574f * (float)(16 + lr));
#pragma unroll
  for (int i = 0; i < 4; i++) {
#pragma unroll
    for (int r = 0; r < 4; r++) {
      int m = m0 + wrow + i * 16 + quad * 4 + r;
      int b = m >> 11, tt = m & 2047;
      size_t base = ((size_t)(b * H_ + h) * T_ + tt) * D_;
      if (which < 2) {
        float sn, cs;
        __sincosf((float)tt * fr0, &sn, &cs);
        dst[base + lr] = f2bf((acc[i][0][r] * cs - acc[i][2][r] * sn) * sc0);
        dst[base + lr + 32] = f2bf((acc[i][0][r] * sn + acc[i][2][r] * cs) * sc0);
        __sincosf((float)tt * fr1, &sn, &cs);
        dst[base + 16 + lr] = f2bf((acc[i][1][r] * cs - acc[i][3][r] * sn) * sc0);
        dst[base + 48 + lr] = f2bf((acc[i][1][r] * sn + acc[i][3][r] * cs) * sc0);
      } else {
#pragma unroll
        for (int j = 0; j < 4; j++) dst[base + j * 16 + lr] = f2bf(acc[i][j][r]);
      }
    }
  }
}

// -------- transpose V: [b,h,t,d] -> [b,h,d,t] --------
__global__ __launch_bounds__(256) void transpose_v(const u16* __restrict__ v,
                                                   u16* __restrict__ vt) {
  __shared__ u16 tile[64][72];
  int t0 = blockIdx.x * 64;
  int bh = blockIdx.y;
  const u16* src = v + (size_t)bh * T_ * D_;
  u16* dst = vt + (size_t)bh * D_ * T_;
  for (int idx = threadIdx.x; idx < 512; idx += 256) {
    int r = idx >> 3, c8 = (idx & 7) * 8;
    *(uint4*)&tile[r][c8] = *(const uint4*)(src + (size_t)(t0 + r) * D_ + c8);
  }
  __syncthreads();
  for (int idx = threadIdx.x; idx < 512; idx += 256) {
    int d = idx >> 3, t8 = (idx & 7) * 8;
    union { uint4 u; u16 s[8]; } p;
#pragma unroll
    for (int e = 0; e < 8; e++) p.s[e] = tile[t8 + e][d];
    *(uint4*)(dst + (size_t)d * T_ + t0 + t8) = p.u;
  }
}

// -------- attention: causal, S^T formulation, q-tile 64 (16 rows/wave), kv-tile 64,
// dbuf + single barrier/iter, heavy-first blocks, XOR-swizzled K/V LDS layout.
// NEW: s_setprio(1) around both MFMA clusters (T5; attn blocks run unsynchronized,
// the proven regime for setprio: +4-7% m191). ----
__global__ __launch_bounds__(256) void attn_k(const u16* __restrict__ qb,
                                              const u16* __restrict__ kb,
                                              const u16* __restrict__ vtb,
                                              u16* __restrict__ ob) {
  __shared__ __align__(16) u16 Ks[2][64 * 64];   // [t][chunk^t&7]
  __shared__ __align__(16) u16 Vt[2][64 * 64];   // [d][chunk^d&7]
  __shared__ __align__(16) u16 Pst[4][16 * 72];  // per-wave P [q=16][t=64 +pad]
  int tid = threadIdx.x;
  int lane = tid & 63, wave = tid >> 6;
  int quad = lane >> 4, lr = lane & 15;
  int i = blockIdx.x;
  int bq = 31 - (i >> 5);  // heavy blocks dispatched first
  int bh = i & 31;
  int b = bh >> 4, h = bh & 15;
  const u16* Q = qb + (size_t)bh * T_ * D_;
  const u16* Kp = kb + (size_t)bh * T_ * D_;
  const u16* Vp = vtb + (size_t)bh * D_ * T_;
  int qr0 = bq * 64 + wave * 16;  // this wave's q-row base
  int r0 = wave * 16;             // staging row base
  int sr = lane >> 3;
  int sc = (((lane & 7) ^ (sr & 7)) * 8);  // XOR-swizzled staging column

  // read-side swizzled chunk offsets (u16 units), constant per lane
  int koff0 = ((quad ^ (lr & 7)) << 3);
  int koff1 = (((4 | quad) ^ (lr & 7)) << 3);

  // Q fragment as MFMA B-operand: B[n=q][k=d] (from global, unswizzled)
  bfrag8 qf[2];
#pragma unroll
  for (int ks = 0; ks < 2; ks++)
    qf[ks] = *(const bfrag8*)(Q + (size_t)(qr0 + lr) * D_ + ks * 32 + quad * 8);

  f32x4 zero = {0.f, 0.f, 0.f, 0.f};
  f32x4 o[4];
#pragma unroll
  for (int nn = 0; nn < 4; nn++) o[nn] = zero;
  float psum = 0.f;

  const u16* gk = Kp + (size_t)(r0 + sr) * D_ + sc;
  const u16* gv = Vp + (size_t)(r0 + sr) * T_ + sc;
  int niter = bq + 1;

  load_lds16(gk, &Ks[0][r0 * 64]);
  load_lds16(gk + (size_t)8 * D_, &Ks[0][(r0 + 8) * 64]);
  load_lds16(gv, &Vt[0][r0 * 64]);
  load_lds16(gv + (size_t)8 * T_, &Vt[0][(r0 + 8) * 64]);

  int buf = 0;
  int qloc = wave * 16 + lr;
  for (int it = 0; it < niter; it++) {
    __syncthreads();  // drains loads for tile `it` (issued one compute-phase ago)
    if (it + 1 < niter) {
      int tkn = (it + 1) * 64;
      load_lds16(gk + (size_t)tkn * D_, &Ks[buf ^ 1][r0 * 64]);
      load_lds16(gk + (size_t)(tkn + 8) * D_, &Ks[buf ^ 1][(r0 + 8) * 64]);
      load_lds16(gv + tkn, &Vt[buf ^ 1][r0 * 64]);
      load_lds16(gv + (size_t)8 * T_ + tkn, &Vt[buf ^ 1][(r0 + 8) * 64]);
    }
    const u16* ks_ = Ks[buf];
    const u16* vt_ = Vt[buf];

    // S^T = K Q^T : 64 kv-rows x 16 q-cols (A=K-frag swizzled, B=Q-frag)
    f32x4 s[4];
#pragma unroll
    for (int j = 0; j < 4; j++) s[j] = zero;
    __builtin_amdgcn_s_setprio(1);
#pragma unroll
    for (int j = 0; j < 4; j++) {
      bfrag8 kf0 = *(const bfrag8*)&ks_[(j * 16 + lr) * 64 + koff0];
      bfrag8 kf1 = *(const bfrag8*)&ks_[(j * 16 + lr) * 64 + koff1];
      s[j] = MFMA_BF16(kf0, qf[0], s[j]);
      s[j] = MFMA_BF16(kf1, qf[1], s[j]);
    }
    __builtin_amdgcn_s_setprio(0);

    // exp + pack pairs (RNE-ish) + ds_write_b64 to Pst[q][t]
    bool edge = (it == bq);  // wave-uniform
#pragma unroll
    for (int j = 0; j < 4; j++) {
      float p[4];
#pragma unroll
      for (int r = 0; r < 4; r++) {
        float e = __expf(s[j][r]);
        if (edge) {
          int kvloc = j * 16 + quad * 4 + r;
          e = (kvloc <= qloc) ? e : 0.f;
        }
        p[r] = e;
        psum += e;
      }
      u32 u0 = __builtin_bit_cast(u32, p[0]) + 0x8000u;
      u32 u1 = __builtin_bit_cast(u32, p[1]) + 0x8000u;
      u32 u2 = __builtin_bit_cast(u32, p[2]) + 0x8000u;
      u32 u3 = __builtin_bit_cast(u32, p[3]) + 0x8000u;
      uint2 pk;
      pk.x = (u0 >> 16) | (u1 & 0xffff0000u);
      pk.y = (u2 >> 16) | (u3 & 0xffff0000u);
      *(uint2*)&Pst[wave][lr * 72 + j * 16 + quad * 4] = pk;
    }

    // O += P V : A = P[q][t] (b128 from Pst), B = V^T[d][t] (swizzled)
    __builtin_amdgcn_s_setprio(1);
#pragma unroll
    for (int ks = 0; ks < 2; ks++) {
      bfrag8 pf = *(const bfrag8*)&Pst[wave][lr * 72 + ks * 32 + quad * 8];
      int ko = ks ? koff1 : koff0;
#pragma unroll
      for (int nn = 0; nn < 4; nn++) {
        bfrag8 vf = *(const bfrag8*)&vt_[(nn * 16 + lr) * 64 + ko];
        o[nn] = MFMA_BF16(pf, vf, o[nn]);
      }
    }
    __builtin_amdgcn_s_setprio(0);
    buf ^= 1;
  }

  // total row-sum: reduce over the 4 quads
  float l = psum;
  l += __shfl_xor(l, 16, 64);
  l += __shfl_xor(l, 32, 64);
  float linv = 1.0f / l;

#pragma unroll
  for (int r = 0; r < 4; r++) {
    float lrec = __shfl(linv, quad * 4 + r, 64);
    int row = qr0 + quad * 4 + r;
#pragma unroll
    for (int nn = 0; nn < 4; nn++)
      ob[(size_t)(b * T_ + row) * C_ + h * 64 + nn * 16 + lr] = f2bf(o[nn][r] * lrec);
  }
}

// -------- GEMM 2: out(f32) = A(4096x1024)bf16 @ WT(1024x1024)bf16 + bias(f32).
// 64x128 tile (grid 512), dbuf LDS, single barrier per iter. --------
__global__ __launch_bounds__(256) void gemm_proj(const u16* __restrict__ A,
                                                 const u16* __restrict__ WT,
                                                 const float* __restrict__ bias,
                                                 float* __restrict__ out) {
  const int K = C_;
  __shared__ __align__(16) u16 As[2][64 * 32];
  __shared__ __align__(16) u16 Bs[2][128 * 32];
  int tid = threadIdx.x;
  int lane = tid & 63, wave = tid >> 6;
  int quad = lane >> 4, lr = lane & 15;
  int m0 = blockIdx.y * 64, n0 = blockIdx.x * 128;
  int wcol = wave * 32;
  int srow = lane >> 2, skc = (lane & 3) * 8;

  f32x4 zero = {0.f, 0.f, 0.f, 0.f};
  f32x4 acc[4][2];
#pragma unroll
  for (int i = 0; i < 4; i++)
#pragma unroll
    for (int j = 0; j < 2; j++) acc[i][j] = zero;

  const u16* ga = A + (size_t)(m0 + wave * 16 + srow) * K + skc;
  const u16* gb0 = WT + (size_t)(n0 + wave * 32 + srow) * K + skc;
  const u16* gb1 = WT + (size_t)(n0 + wave * 32 + 16 + srow) * K + skc;

  load_lds16(ga, &As[0][wave * 16 * 32]);
  load_lds16(gb0, &Bs[0][wave * 32 * 32]);
  load_lds16(gb1, &Bs[0][(wave * 32 + 16) * 32]);

  int buf = 0;
  for (int k0 = 0; k0 < K; k0 += 32) {
    __syncthreads();
    if (k0 + 32 < K) {
      load_lds16(ga + k0 + 32, &As[buf ^ 1][wave * 16 * 32]);
      load_lds16(gb0 + k0 + 32, &Bs[buf ^ 1][wave * 32 * 32]);
      load_lds16(gb1 + k0 + 32, &Bs[buf ^ 1][(wave * 32 + 16) * 32]);
    }
    bfrag8 af[4], bfr[2];
#pragma unroll
    for (int i = 0; i < 4; i++)
      af[i] = *(const bfrag8*)&As[buf][(i * 16 + lr) * 32 + quad * 8];
#pragma unroll
    for (int j = 0; j < 2; j++)
      bfr[j] = *(const bfrag8*)&Bs[buf][(wcol + j * 16 + lr) * 32 + quad * 8];
#pragma unroll
    for (int i = 0; i < 4; i++)
#pragma unroll
      for (int j = 0; j < 2; j++) acc[i][j] = MFMA_BF16(af[i], bfr[j], acc[i][j]);
    buf ^= 1;
  }

#pragma unroll
  for (int i = 0; i < 4; i++)
#pragma unroll
    for (int r = 0; r < 4; r++) {
      int m = m0 + i * 16 + quad * 4 + r;
#pragma unroll
      for (int j = 0; j < 2; j++) {
        int n = n0 + wcol + j * 16 + lr;
        out[(size_t)m * C_ + n] = acc[i][j][r] + bias[n];
      }
    }
}

extern "C" void kernel_launch(void* const* d_in, const int* in_sizes, int n_in,
                              void* d_out, int out_size, void* d_ws, size_t ws_size,
                              hipStream_t stream) {
  const float* x = (const float*)d_in[0];       // [4096,1024] f32
  const float* w_qkv = (const float*)d_in[1];   // [1024,3072] f32
  const float* w_proj = (const float*)d_in[2];  // [1024,1024] f32
  const float* b_proj = (const float*)d_in[3];  // [1024] f32

  char* w = (char*)d_ws;
  u16* vtb = (u16*)(w + 256);                // 2*16*64*2048 bf16 (V^T)
  u16* regA = vtb + (size_t)4096 * 1024;     // max(wqkvT, abuf)
  u16* wqkvT = regA;                         // 3072*1024 (dead after gemm_qkv)
  u16* abuf = regA;                          // 4096*1024 (written by attn)
  u16* wprojT = regA + (size_t)4096 * 1024;  // 1024*1024
  u16* qbuf = wprojT + (size_t)1024 * 1024;
  u16* kbuf = qbuf + (size_t)B_ * H_ * T_ * D_;
  u16* vbuf = kbuf + (size_t)B_ * H_ * T_ * D_;

  transpose_w<<<dim3(NQKV_ / 64, C_ / 64), 256, 0, stream>>>(w_qkv, wqkvT, C_, NQKV_);
  transpose_w<<<dim3(C_ / 64, C_ / 64), 256, 0, stream>>>(w_proj, wprojT, C_, C_);
  gemm_qkv_rope<<<dim3(NQKV_ / 128, (B_ * T_) / 128), 256, 0, stream>>>(x, wqkvT, qbuf, kbuf, vbuf);
  transpose_v<<<dim3(T_ / 64, B_ * H_), 256, 0, stream>>>(vbuf, vtb);
  attn_k<<<1024, 256, 0, stream>>>(qbuf, kbuf, vtb, abuf);
  gemm_proj<<<dim3(C_ / 128, (B_ * T_) / 64), 256, 0, stream>>>(abuf, wprojT, b_proj, (float*)d_out);
}

// Round 4
// 199.210 us; speedup vs baseline: 1.1708x; 1.1708x over previous
//
#include <hip/hip_runtime.h>
#include <math.h>

typedef unsigned short u16;
typedef unsigned int u32;
typedef __bf16 bfrag8 __attribute__((ext_vector_type(8)));
typedef float f32x4 __attribute__((ext_vector_type(4)));

#define B_ 2
#define T_ 2048
#define H_ 16
#define D_ 64
#define C_ 1024
#define NQKV_ 3072

#define MFMA_BF16(a, b, c) __builtin_amdgcn_mfma_f32_16x16x32_bf16((a), (b), (c), 0, 0, 0)

__device__ __forceinline__ u16 f2bf(float f) {
  u32 u = __builtin_bit_cast(u32, f);
  u += 0x7fffu + ((u >> 16) & 1u);  // RNE
  return (u16)(u >> 16);
}

// async global->LDS, 16B/lane; lds dest = wave-uniform base + lane*16
__device__ __forceinline__ void load_lds16(const u16* gp, u16* lp) {
  __builtin_amdgcn_global_load_lds(
      (const __attribute__((address_space(1))) u32*)(const void*)gp,
      (__attribute__((address_space(3))) u32*)(void*)lp, 16, 0, 0);
}

// raw barrier with compiler motion fences (keep ds_reads inside their phase)
__device__ __forceinline__ void block_barrier() {
  __builtin_amdgcn_sched_barrier(0);
  asm volatile("" ::: "memory");
  __builtin_amdgcn_s_barrier();
  asm volatile("" ::: "memory");
  __builtin_amdgcn_sched_barrier(0);
}

// -------- convert x (f32) -> bf16 --------
__global__ __launch_bounds__(256) void convert_x(const float* __restrict__ src,
                                                 u16* __restrict__ dst) {
  size_t i = ((size_t)blockIdx.x * 256 + threadIdx.x) * 8;
  const float* s = src + i;
  float4 a = *(const float4*)s, b = *(const float4*)(s + 4);
  union { uint4 v; u16 h[8]; } t;
  t.h[0] = f2bf(a.x); t.h[1] = f2bf(a.y); t.h[2] = f2bf(a.z); t.h[3] = f2bf(a.w);
  t.h[4] = f2bf(b.x); t.h[5] = f2bf(b.y); t.h[6] = f2bf(b.z); t.h[7] = f2bf(b.w);
  *(uint4*)(dst + i) = t.v;
}

// -------- transpose+convert weight: src f32 [K][N] -> dst bf16 [N][K] --------
__global__ __launch_bounds__(256) void transpose_w(const float* __restrict__ src,
                                                   u16* __restrict__ dst, int K, int N) {
  __shared__ u16 tile[64][65];
  int bx = blockIdx.x * 64;  // over N
  int by = blockIdx.y * 64;  // over K
  for (int idx = threadIdx.x; idx < 4096; idx += 256) {
    int r = idx >> 6, c = idx & 63;
    tile[r][c] = f2bf(src[(size_t)(by + r) * N + bx + c]);
  }
  __syncthreads();
  for (int idx = threadIdx.x; idx < 4096; idx += 256) {
    int r = idx >> 6, c = idx & 63;
    dst[(size_t)(bx + r) * K + by + c] = tile[c][r];
  }
}

// -------- GEMM 1: qkv = X(4096x1024)bf16 @ WT(3072x1024)bf16, RoPE(+q*1/8) epilogue.
// Round-0 structure + depth-2 prefetch: TRIPLE-buffered LDS, counted vmcnt(4)
// (tile t+1's 4 loads stay in flight across the barrier; staging gets ~2 compute
// phases to cover HBM latency instead of <1). Raw s_barrier + fences (validated r2).
__global__ __launch_bounds__(256) void gemm_qkv_rope(const u16* __restrict__ X,
                                                     const u16* __restrict__ WT,
                                                     u16* __restrict__ qb,
                                                     u16* __restrict__ kb,
                                                     u16* __restrict__ vb) {
  const int K = C_;
  const int NTI = 32;  // K / 32
  __shared__ __align__(16) u16 As[3][128 * 32];
  __shared__ __align__(16) u16 Bs[3][128 * 32];
  int tid = threadIdx.x;
  int lane = tid & 63, wave = tid >> 6;
  int quad = lane >> 4, lr = lane & 15;
  int m0 = blockIdx.y * 128, n0 = blockIdx.x * 128;
  int wrow = (wave >> 1) * 64, wcol = (wave & 1) * 64;
  int r0 = wave * 32;
  int srow = lane >> 2, skc = (lane & 3) * 8;

  f32x4 zero = {0.f, 0.f, 0.f, 0.f};
  f32x4 acc[4][4];
#pragma unroll
  for (int i = 0; i < 4; i++)
#pragma unroll
    for (int j = 0; j < 4; j++) acc[i][j] = zero;

  const u16* ga0 = X + (size_t)(m0 + r0 + srow) * K + skc;
  const u16* ga1 = X + (size_t)(m0 + r0 + 16 + srow) * K + skc;
  const u16* gb0 = WT + (size_t)(n0 + r0 + srow) * K + skc;
  const u16* gb1 = WT + (size_t)(n0 + r0 + 16 + srow) * K + skc;

  // prologue: tiles 0 and 1 in flight (8 loads/thread)
  load_lds16(ga0, &As[0][r0 * 32]);
  load_lds16(ga1, &As[0][(r0 + 16) * 32]);
  load_lds16(gb0, &Bs[0][r0 * 32]);
  load_lds16(gb1, &Bs[0][(r0 + 16) * 32]);
  load_lds16(ga0 + 32, &As[1][r0 * 32]);
  load_lds16(ga1 + 32, &As[1][(r0 + 16) * 32]);
  load_lds16(gb0 + 32, &Bs[1][r0 * 32]);
  load_lds16(gb1 + 32, &Bs[1][(r0 + 16) * 32]);

  int bc = 0;  // current buffer (kt % 3)
#pragma unroll 1
  for (int kt = 0; kt < NTI; kt++) {
    // tile kt landed; tile kt+1's 4 loads stay in flight across the barrier
    if (kt < NTI - 1) {
      asm volatile("s_waitcnt vmcnt(4)" ::: "memory");
    } else {
      asm volatile("s_waitcnt vmcnt(0)" ::: "memory");
    }
    __builtin_amdgcn_sched_barrier(0);
    block_barrier();  // tile kt visible to all waves; buf[(kt+2)%3] free (read at kt-1)
    if (kt < NTI - 2) {
      int bn = bc + 2; if (bn >= 3) bn -= 3;
      int kn = kt * 32 + 64;
      load_lds16(ga0 + kn, &As[bn][r0 * 32]);
      load_lds16(ga1 + kn, &As[bn][(r0 + 16) * 32]);
      load_lds16(gb0 + kn, &Bs[bn][r0 * 32]);
      load_lds16(gb1 + kn, &Bs[bn][(r0 + 16) * 32]);
    }
    bfrag8 af[4], bfr[4];
#pragma unroll
    for (int i = 0; i < 4; i++)
      af[i] = *(const bfrag8*)&As[bc][(wrow + i * 16 + lr) * 32 + quad * 8];
#pragma unroll
    for (int j = 0; j < 4; j++)
      bfr[j] = *(const bfrag8*)&Bs[bc][(wcol + j * 16 + lr) * 32 + quad * 8];
#pragma unroll
    for (int i = 0; i < 4; i++)
#pragma unroll
      for (int j = 0; j < 4; j++) acc[i][j] = MFMA_BF16(af[i], bfr[j], acc[i][j]);
    bc = (bc == 2) ? 0 : bc + 1;
  }

  int colbase = n0 + wcol;
  int which = colbase >> 10;  // 0=q 1=k 2=v
  int h = (colbase & 1023) >> 6;
  u16* dst = which == 0 ? qb : (which == 1 ? kb : vb);
  float sc0 = (which == 0) ? 0.125f : 1.0f;
  float fr0 = __expf(-0.28782313662425574f * (float)lr);        // ln(10000)/32
  float fr1 = __expf(-0.28782313662425574f * (float)(16 + lr));
#pragma unroll
  for (int i = 0; i < 4; i++) {
#pragma unroll
    for (int r = 0; r < 4; r++) {
      int m = m0 + wrow + i * 16 + quad * 4 + r;
      int b = m >> 11, tt = m & 2047;
      size_t base = ((size_t)(b * H_ + h) * T_ + tt) * D_;
      if (which < 2) {
        float sn, cs;
        __sincosf((float)tt * fr0, &sn, &cs);
        dst[base + lr] = f2bf((acc[i][0][r] * cs - acc[i][2][r] * sn) * sc0);
        dst[base + lr + 32] = f2bf((acc[i][0][r] * sn + acc[i][2][r] * cs) * sc0);
        __sincosf((float)tt * fr1, &sn, &cs);
        dst[base + 16 + lr] = f2bf((acc[i][1][r] * cs - acc[i][3][r] * sn) * sc0);
        dst[base + 48 + lr] = f2bf((acc[i][1][r] * sn + acc[i][3][r] * cs) * sc0);
      } else {
#pragma unroll
        for (int j = 0; j < 4; j++) dst[base + j * 16 + lr] = f2bf(acc[i][j][r]);
      }
    }
  }
}

// -------- transpose V: [b,h,t,d] -> [b,h,d,t] --------
__global__ __launch_bounds__(256) void transpose_v(const u16* __restrict__ v,
                                                   u16* __restrict__ vt) {
  __shared__ u16 tile[64][72];
  int t0 = blockIdx.x * 64;
  int bh = blockIdx.y;
  const u16* src = v + (size_t)bh * T_ * D_;
  u16* dst = vt + (size_t)bh * D_ * T_;
  for (int idx = threadIdx.x; idx < 512; idx += 256) {
    int r = idx >> 3, c8 = (idx & 7) * 8;
    *(uint4*)&tile[r][c8] = *(const uint4*)(src + (size_t)(t0 + r) * D_ + c8);
  }
  __syncthreads();
  for (int idx = threadIdx.x; idx < 512; idx += 256) {
    int d = idx >> 3, t8 = (idx & 7) * 8;
    union { uint4 u; u16 s[8]; } p;
#pragma unroll
    for (int e = 0; e < 8; e++) p.s[e] = tile[t8 + e][d];
    *(uint4*)(dst + (size_t)d * T_ + t0 + t8) = p.u;
  }
}

// -------- attention: causal, S^T formulation, q-tile 64 (16 rows/wave), kv-tile 64,
// dbuf + single barrier/iter, heavy-first blocks, XOR-swizzled K/V LDS layout.
// (round-0 exact: setprio removed — 4-wave lockstep is the m190 null regime) ----
__global__ __launch_bounds__(256) void attn_k(const u16* __restrict__ qb,
                                              const u16* __restrict__ kb,
                                              const u16* __restrict__ vtb,
                                              u16* __restrict__ ob) {
  __shared__ __align__(16) u16 Ks[2][64 * 64];   // [t][chunk^t&7]
  __shared__ __align__(16) u16 Vt[2][64 * 64];   // [d][chunk^d&7]
  __shared__ __align__(16) u16 Pst[4][16 * 72];  // per-wave P [q=16][t=64 +pad]
  int tid = threadIdx.x;
  int lane = tid & 63, wave = tid >> 6;
  int quad = lane >> 4, lr = lane & 15;
  int i = blockIdx.x;
  int bq = 31 - (i >> 5);  // heavy blocks dispatched first
  int bh = i & 31;
  int b = bh >> 4, h = bh & 15;
  const u16* Q = qb + (size_t)bh * T_ * D_;
  const u16* Kp = kb + (size_t)bh * T_ * D_;
  const u16* Vp = vtb + (size_t)bh * D_ * T_;
  int qr0 = bq * 64 + wave * 16;  // this wave's q-row base
  int r0 = wave * 16;             // staging row base
  int sr = lane >> 3;
  int sc = (((lane & 7) ^ (sr & 7)) * 8);  // XOR-swizzled staging column

  // read-side swizzled chunk offsets (u16 units), constant per lane
  int koff0 = ((quad ^ (lr & 7)) << 3);
  int koff1 = (((4 | quad) ^ (lr & 7)) << 3);

  // Q fragment as MFMA B-operand: B[n=q][k=d] (from global, unswizzled)
  bfrag8 qf[2];
#pragma unroll
  for (int ks = 0; ks < 2; ks++)
    qf[ks] = *(const bfrag8*)(Q + (size_t)(qr0 + lr) * D_ + ks * 32 + quad * 8);

  f32x4 zero = {0.f, 0.f, 0.f, 0.f};
  f32x4 o[4];
#pragma unroll
  for (int nn = 0; nn < 4; nn++) o[nn] = zero;
  float psum = 0.f;

  const u16* gk = Kp + (size_t)(r0 + sr) * D_ + sc;
  const u16* gv = Vp + (size_t)(r0 + sr) * T_ + sc;
  int niter = bq + 1;

  load_lds16(gk, &Ks[0][r0 * 64]);
  load_lds16(gk + (size_t)8 * D_, &Ks[0][(r0 + 8) * 64]);
  load_lds16(gv, &Vt[0][r0 * 64]);
  load_lds16(gv + (size_t)8 * T_, &Vt[0][(r0 + 8) * 64]);

  int buf = 0;
  int qloc = wave * 16 + lr;
  for (int it = 0; it < niter; it++) {
    __syncthreads();  // drains loads for tile `it` (issued one compute-phase ago)
    if (it + 1 < niter) {
      int tkn = (it + 1) * 64;
      load_lds16(gk + (size_t)tkn * D_, &Ks[buf ^ 1][r0 * 64]);
      load_lds16(gk + (size_t)(tkn + 8) * D_, &Ks[buf ^ 1][(r0 + 8) * 64]);
      load_lds16(gv + tkn, &Vt[buf ^ 1][r0 * 64]);
      load_lds16(gv + (size_t)8 * T_ + tkn, &Vt[buf ^ 1][(r0 + 8) * 64]);
    }
    const u16* ks_ = Ks[buf];
    const u16* vt_ = Vt[buf];

    // S^T = K Q^T : 64 kv-rows x 16 q-cols (A=K-frag swizzled, B=Q-frag)
    f32x4 s[4];
#pragma unroll
    for (int j = 0; j < 4; j++) s[j] = zero;
#pragma unroll
    for (int j = 0; j < 4; j++) {
      bfrag8 kf0 = *(const bfrag8*)&ks_[(j * 16 + lr) * 64 + koff0];
      bfrag8 kf1 = *(const bfrag8*)&ks_[(j * 16 + lr) * 64 + koff1];
      s[j] = MFMA_BF16(kf0, qf[0], s[j]);
      s[j] = MFMA_BF16(kf1, qf[1], s[j]);
    }

    // exp + pack pairs (RNE-ish) + ds_write_b64 to Pst[q][t]
    bool edge = (it == bq);  // wave-uniform
#pragma unroll
    for (int j = 0; j < 4; j++) {
      float p[4];
#pragma unroll
      for (int r = 0; r < 4; r++) {
        float e = __expf(s[j][r]);
        if (edge) {
          int kvloc = j * 16 + quad * 4 + r;
          e = (kvloc <= qloc) ? e : 0.f;
        }
        p[r] = e;
        psum += e;
      }
      u32 u0 = __builtin_bit_cast(u32, p[0]) + 0x8000u;
      u32 u1 = __builtin_bit_cast(u32, p[1]) + 0x8000u;
      u32 u2 = __builtin_bit_cast(u32, p[2]) + 0x8000u;
      u32 u3 = __builtin_bit_cast(u32, p[3]) + 0x8000u;
      uint2 pk;
      pk.x = (u0 >> 16) | (u1 & 0xffff0000u);
      pk.y = (u2 >> 16) | (u3 & 0xffff0000u);
      *(uint2*)&Pst[wave][lr * 72 + j * 16 + quad * 4] = pk;
    }

    // O += P V : A = P[q][t] (b128 from Pst), B = V^T[d][t] (swizzled)
#pragma unroll
    for (int ks = 0; ks < 2; ks++) {
      bfrag8 pf = *(const bfrag8*)&Pst[wave][lr * 72 + ks * 32 + quad * 8];
      int ko = ks ? koff1 : koff0;
#pragma unroll
      for (int nn = 0; nn < 4; nn++) {
        bfrag8 vf = *(const bfrag8*)&vt_[(nn * 16 + lr) * 64 + ko];
        o[nn] = MFMA_BF16(pf, vf, o[nn]);
      }
    }
    buf ^= 1;
  }

  // total row-sum: reduce over the 4 quads
  float l = psum;
  l += __shfl_xor(l, 16, 64);
  l += __shfl_xor(l, 32, 64);
  float linv = 1.0f / l;

#pragma unroll
  for (int r = 0; r < 4; r++) {
    float lrec = __shfl(linv, quad * 4 + r, 64);
    int row = qr0 + quad * 4 + r;
#pragma unroll
    for (int nn = 0; nn < 4; nn++)
      ob[(size_t)(b * T_ + row) * C_ + h * 64 + nn * 16 + lr] = f2bf(o[nn][r] * lrec);
  }
}

// -------- GEMM 2: out(f32) = A(4096x1024)bf16 @ WT(1024x1024)bf16 + bias(f32).
// 64x128 tile (grid 512). Same depth-2 prefetch as GEMM 1: triple-buffer,
// counted vmcnt(3) (3 loads/thread/tile). --------
__global__ __launch_bounds__(256) void gemm_proj(const u16* __restrict__ A,
                                                 const u16* __restrict__ WT,
                                                 const float* __restrict__ bias,
                                                 float* __restrict__ out) {
  const int K = C_;
  const int NTI = 32;
  __shared__ __align__(16) u16 As[3][64 * 32];
  __shared__ __align__(16) u16 Bs[3][128 * 32];
  int tid = threadIdx.x;
  int lane = tid & 63, wave = tid >> 6;
  int quad = lane >> 4, lr = lane & 15;
  int m0 = blockIdx.y * 64, n0 = blockIdx.x * 128;
  int wcol = wave * 32;
  int srow = lane >> 2, skc = (lane & 3) * 8;

  f32x4 zero = {0.f, 0.f, 0.f, 0.f};
  f32x4 acc[4][2];
#pragma unroll
  for (int i = 0; i < 4; i++)
#pragma unroll
    for (int j = 0; j < 2; j++) acc[i][j] = zero;

  const u16* ga = A + (size_t)(m0 + wave * 16 + srow) * K + skc;
  const u16* gb0 = WT + (size_t)(n0 + wave * 32 + srow) * K + skc;
  const u16* gb1 = WT + (size_t)(n0 + wave * 32 + 16 + srow) * K + skc;

  load_lds16(ga, &As[0][wave * 16 * 32]);
  load_lds16(gb0, &Bs[0][wave * 32 * 32]);
  load_lds16(gb1, &Bs[0][(wave * 32 + 16) * 32]);
  load_lds16(ga + 32, &As[1][wave * 16 * 32]);
  load_lds16(gb0 + 32, &Bs[1][wave * 32 * 32]);
  load_lds16(gb1 + 32, &Bs[1][(wave * 32 + 16) * 32]);

  int bc = 0;
#pragma unroll 1
  for (int kt = 0; kt < NTI; kt++) {
    if (kt < NTI - 1) {
      asm volatile("s_waitcnt vmcnt(3)" ::: "memory");
    } else {
      asm volatile("s_waitcnt vmcnt(0)" ::: "memory");
    }
    __builtin_amdgcn_sched_barrier(0);
    block_barrier();
    if (kt < NTI - 2) {
      int bn = bc + 2; if (bn >= 3) bn -= 3;
      int kn = kt * 32 + 64;
      load_lds16(ga + kn, &As[bn][wave * 16 * 32]);
      load_lds16(gb0 + kn, &Bs[bn][wave * 32 * 32]);
      load_lds16(gb1 + kn, &Bs[bn][(wave * 32 + 16) * 32]);
    }
    bfrag8 af[4], bfr[2];
#pragma unroll
    for (int i = 0; i < 4; i++)
      af[i] = *(const bfrag8*)&As[bc][(i * 16 + lr) * 32 + quad * 8];
#pragma unroll
    for (int j = 0; j < 2; j++)
      bfr[j] = *(const bfrag8*)&Bs[bc][(wcol + j * 16 + lr) * 32 + quad * 8];
#pragma unroll
    for (int i = 0; i < 4; i++)
#pragma unroll
      for (int j = 0; j < 2; j++) acc[i][j] = MFMA_BF16(af[i], bfr[j], acc[i][j]);
    bc = (bc == 2) ? 0 : bc + 1;
  }

#pragma unroll
  for (int i = 0; i < 4; i++)
#pragma unroll
    for (int r = 0; r < 4; r++) {
      int m = m0 + i * 16 + quad * 4 + r;
#pragma unroll
      for (int j = 0; j < 2; j++) {
        int n = n0 + wcol + j * 16 + lr;
        out[(size_t)m * C_ + n] = acc[i][j][r] + bias[n];
      }
    }
}

extern "C" void kernel_launch(void* const* d_in, const int* in_sizes, int n_in,
                              void* d_out, int out_size, void* d_ws, size_t ws_size,
                              hipStream_t stream) {
  const float* x = (const float*)d_in[0];       // [4096,1024] f32
  const float* w_qkv = (const float*)d_in[1];   // [1024,3072] f32
  const float* w_proj = (const float*)d_in[2];  // [1024,1024] f32
  const float* b_proj = (const float*)d_in[3];  // [1024] f32

  char* w = (char*)d_ws;
  u16* xb = (u16*)(w + 256);                 // 4096*1024 bf16
  u16* vtb = xb;                             // alias: used after xb is dead
  u16* regA = xb + (size_t)4096 * 1024;      // max(wqkvT, abuf)
  u16* wqkvT = regA;                         // 3072*1024 (dead after gemm_qkv)
  u16* abuf = regA;                          // 4096*1024 (written by attn)
  u16* wprojT = regA + (size_t)4096 * 1024;  // 1024*1024
  u16* qbuf = wprojT + (size_t)1024 * 1024;
  u16* kbuf = qbuf + (size_t)B_ * H_ * T_ * D_;
  u16* vbuf = kbuf + (size_t)B_ * H_ * T_ * D_;

  convert_x<<<2048, 256, 0, stream>>>(x, xb);
  transpose_w<<<dim3(NQKV_ / 64, C_ / 64), 256, 0, stream>>>(w_qkv, wqkvT, C_, NQKV_);
  transpose_w<<<dim3(C_ / 64, C_ / 64), 256, 0, stream>>>(w_proj, wprojT, C_, C_);
  gemm_qkv_rope<<<dim3(NQKV_ / 128, (B_ * T_) / 128), 256, 0, stream>>>(xb, wqkvT, qbuf, kbuf, vbuf);
  transpose_v<<<dim3(T_ / 64, B_ * H_), 256, 0, stream>>>(vbuf, vtb);
  attn_k<<<1024, 256, 0, stream>>>(qbuf, kbuf, vtb, abuf);
  gemm_proj<<<dim3(C_ / 128, (B_ * T_) / 64), 256, 0, stream>>>(abuf, wprojT, b_proj, (float*)d_out);
}

// Round 5
// 193.879 us; speedup vs baseline: 1.2030x; 1.0275x over previous
//
#include <hip/hip_runtime.h>
#include <math.h>

typedef unsigned short u16;
typedef unsigned int u32;
typedef __bf16 bfrag8 __attribute__((ext_vector_type(8)));
typedef float f32x4 __attribute__((ext_vector_type(4)));

#define B_ 2
#define T_ 2048
#define H_ 16
#define D_ 64
#define C_ 1024
#define NQKV_ 3072

#define MFMA_BF16(a, b, c) __builtin_amdgcn_mfma_f32_16x16x32_bf16((a), (b), (c), 0, 0, 0)

__device__ __forceinline__ u16 f2bf(float f) {
  u32 u = __builtin_bit_cast(u32, f);
  u += 0x7fffu + ((u >> 16) & 1u);  // RNE
  return (u16)(u >> 16);
}

// async global->LDS, 16B/lane; lds dest = wave-uniform base + lane*16
__device__ __forceinline__ void load_lds16(const u16* gp, u16* lp) {
  __builtin_amdgcn_global_load_lds(
      (const __attribute__((address_space(1))) u32*)(const void*)gp,
      (__attribute__((address_space(3))) u32*)(void*)lp, 16, 0, 0);
}

// -------- convert x (f32) -> bf16 --------
__global__ __launch_bounds__(256) void convert_x(const float* __restrict__ src,
                                                 u16* __restrict__ dst) {
  size_t i = ((size_t)blockIdx.x * 256 + threadIdx.x) * 8;
  const float* s = src + i;
  float4 a = *(const float4*)s, b = *(const float4*)(s + 4);
  union { uint4 v; u16 h[8]; } t;
  t.h[0] = f2bf(a.x); t.h[1] = f2bf(a.y); t.h[2] = f2bf(a.z); t.h[3] = f2bf(a.w);
  t.h[4] = f2bf(b.x); t.h[5] = f2bf(b.y); t.h[6] = f2bf(b.z); t.h[7] = f2bf(b.w);
  *(uint4*)(dst + i) = t.v;
}

// -------- transpose+convert weight: src f32 [K][N] -> dst bf16 [N][K] --------
__global__ __launch_bounds__(256) void transpose_w(const float* __restrict__ src,
                                                   u16* __restrict__ dst, int K, int N) {
  __shared__ u16 tile[64][65];
  int bx = blockIdx.x * 64;  // over N
  int by = blockIdx.y * 64;  // over K
  for (int idx = threadIdx.x; idx < 4096; idx += 256) {
    int r = idx >> 6, c = idx & 63;
    tile[r][c] = f2bf(src[(size_t)(by + r) * N + bx + c]);
  }
  __syncthreads();
  for (int idx = threadIdx.x; idx < 4096; idx += 256) {
    int r = idx >> 6, c = idx & 63;
    dst[(size_t)(bx + r) * K + by + c] = tile[c][r];
  }
}

// -------- GEMM 1: qkv = X(4096x1024)bf16 @ WT(3072x1024)bf16, RoPE(+q*1/8) epilogue.
// 128x128 tile, BK=64 (16 iters: halves the per-iter barrier overhead that r4's
// counted-vmcnt null isolated as the stall), dbuf LDS + __syncthreads (proven r0 sync).
// 128B LDS rows would be a 32-way bank conflict -> chunk-XOR swizzle (attn-proven):
// LDS[row][c] holds global 16B-chunk c^(row&7); staging source pre-swizzled,
// ds_read applies the same involution. Kills r0's 3.1M conflict cycles too. --------
__global__ __launch_bounds__(256) void gemm_qkv_rope(const u16* __restrict__ X,
                                                     const u16* __restrict__ WT,
                                                     u16* __restrict__ qb,
                                                     u16* __restrict__ kb,
                                                     u16* __restrict__ vb) {
  const int K = C_;
  __shared__ __align__(16) u16 As[2][128 * 64];  // 32 KB
  __shared__ __align__(16) u16 Bs[2][128 * 64];  // 32 KB
  int tid = threadIdx.x;
  int lane = tid & 63, wave = tid >> 6;
  int quad = lane >> 4, lr = lane & 15;
  int m0 = blockIdx.y * 128, n0 = blockIdx.x * 128;
  int wrow = (wave >> 1) * 64, wcol = (wave & 1) * 64;
  int r0 = wave * 32;  // this wave's staging row base (32 rows per wave)
  int srow = lane >> 3;
  int schunk = (lane & 7) ^ srow;  // pre-swizzled global source chunk

  // read-side swizzled chunk offsets (u16 units): logical chunk (ks*4+quad) ^ (row&7)
  int koff0 = ((quad ^ (lr & 7)) << 3);
  int koff1 = (((4 | quad) ^ (lr & 7)) << 3);

  f32x4 zero = {0.f, 0.f, 0.f, 0.f};
  f32x4 acc[4][4];
#pragma unroll
  for (int i = 0; i < 4; i++)
#pragma unroll
    for (int j = 0; j < 4; j++) acc[i][j] = zero;

  const u16* ga = X + (size_t)(m0 + r0 + srow) * K + schunk * 8;
  const u16* gb = WT + (size_t)(n0 + r0 + srow) * K + schunk * 8;

  // prologue: stage tile 0 (8 loads/thread: 4 A-rowgroups + 4 B-rowgroups)
#pragma unroll
  for (int l = 0; l < 4; l++) {
    load_lds16(ga + (size_t)(l * 8) * K, &As[0][(r0 + l * 8) * 64]);
    load_lds16(gb + (size_t)(l * 8) * K, &Bs[0][(r0 + l * 8) * 64]);
  }

  int buf = 0;
  for (int k0 = 0; k0 < K; k0 += 64) {
    __syncthreads();  // drains tile-k0 loads (issued one compute phase ago)
    if (k0 + 64 < K) {
#pragma unroll
      for (int l = 0; l < 4; l++) {
        load_lds16(ga + (size_t)(l * 8) * K + k0 + 64, &As[buf ^ 1][(r0 + l * 8) * 64]);
        load_lds16(gb + (size_t)(l * 8) * K + k0 + 64, &Bs[buf ^ 1][(r0 + l * 8) * 64]);
      }
    }
    bfrag8 af[4][2], bf[4][2];
#pragma unroll
    for (int i = 0; i < 4; i++) {
      const u16* ar = &As[buf][(wrow + i * 16 + lr) * 64];
      af[i][0] = *(const bfrag8*)(ar + koff0);
      af[i][1] = *(const bfrag8*)(ar + koff1);
    }
#pragma unroll
    for (int j = 0; j < 4; j++) {
      const u16* br = &Bs[buf][(wcol + j * 16 + lr) * 64];
      bf[j][0] = *(const bfrag8*)(br + koff0);
      bf[j][1] = *(const bfrag8*)(br + koff1);
    }
#pragma unroll
    for (int i = 0; i < 4; i++)
#pragma unroll
      for (int j = 0; j < 4; j++) {
        acc[i][j] = MFMA_BF16(af[i][0], bf[j][0], acc[i][j]);
        acc[i][j] = MFMA_BF16(af[i][1], bf[j][1], acc[i][j]);
      }
    buf ^= 1;
  }

  int colbase = n0 + wcol;
  int which = colbase >> 10;  // 0=q 1=k 2=v
  int h = (colbase & 1023) >> 6;
  u16* dst = which == 0 ? qb : (which == 1 ? kb : vb);
  float sc0 = (which == 0) ? 0.125f : 1.0f;
  float fr0 = __expf(-0.28782313662425574f * (float)lr);        // ln(10000)/32
  float fr1 = __expf(-0.28782313662425574f * (float)(16 + lr));
#pragma unroll
  for (int i = 0; i < 4; i++) {
#pragma unroll
    for (int r = 0; r < 4; r++) {
      int m = m0 + wrow + i * 16 + quad * 4 + r;
      int b = m >> 11, tt = m & 2047;
      size_t base = ((size_t)(b * H_ + h) * T_ + tt) * D_;
      if (which < 2) {
        float sn, cs;
        __sincosf((float)tt * fr0, &sn, &cs);
        dst[base + lr] = f2bf((acc[i][0][r] * cs - acc[i][2][r] * sn) * sc0);
        dst[base + lr + 32] = f2bf((acc[i][0][r] * sn + acc[i][2][r] * cs) * sc0);
        __sincosf((float)tt * fr1, &sn, &cs);
        dst[base + 16 + lr] = f2bf((acc[i][1][r] * cs - acc[i][3][r] * sn) * sc0);
        dst[base + 48 + lr] = f2bf((acc[i][1][r] * sn + acc[i][3][r] * cs) * sc0);
      } else {
#pragma unroll
        for (int j = 0; j < 4; j++) dst[base + j * 16 + lr] = f2bf(acc[i][j][r]);
      }
    }
  }
}

// -------- transpose V: [b,h,t,d] -> [b,h,d,t] --------
__global__ __launch_bounds__(256) void transpose_v(const u16* __restrict__ v,
                                                   u16* __restrict__ vt) {
  __shared__ u16 tile[64][72];
  int t0 = blockIdx.x * 64;
  int bh = blockIdx.y;
  const u16* src = v + (size_t)bh * T_ * D_;
  u16* dst = vt + (size_t)bh * D_ * T_;
  for (int idx = threadIdx.x; idx < 512; idx += 256) {
    int r = idx >> 3, c8 = (idx & 7) * 8;
    *(uint4*)&tile[r][c8] = *(const uint4*)(src + (size_t)(t0 + r) * D_ + c8);
  }
  __syncthreads();
  for (int idx = threadIdx.x; idx < 512; idx += 256) {
    int d = idx >> 3, t8 = (idx & 7) * 8;
    union { uint4 u; u16 s[8]; } p;
#pragma unroll
    for (int e = 0; e < 8; e++) p.s[e] = tile[t8 + e][d];
    *(uint4*)(dst + (size_t)d * T_ + t0 + t8) = p.u;
  }
}

// -------- attention: causal, S^T formulation, q-tile 64 (16 rows/wave), kv-tile 64,
// dbuf + single barrier/iter, heavy-first blocks, XOR-swizzled K/V LDS layout. ----
__global__ __launch_bounds__(256) void attn_k(const u16* __restrict__ qb,
                                              const u16* __restrict__ kb,
                                              const u16* __restrict__ vtb,
                                              u16* __restrict__ ob) {
  __shared__ __align__(16) u16 Ks[2][64 * 64];   // [t][chunk^t&7]
  __shared__ __align__(16) u16 Vt[2][64 * 64];   // [d][chunk^d&7]
  __shared__ __align__(16) u16 Pst[4][16 * 72];  // per-wave P [q=16][t=64 +pad]
  int tid = threadIdx.x;
  int lane = tid & 63, wave = tid >> 6;
  int quad = lane >> 4, lr = lane & 15;
  int i = blockIdx.x;
  int bq = 31 - (i >> 5);  // heavy blocks dispatched first
  int bh = i & 31;
  int b = bh >> 4, h = bh & 15;
  const u16* Q = qb + (size_t)bh * T_ * D_;
  const u16* Kp = kb + (size_t)bh * T_ * D_;
  const u16* Vp = vtb + (size_t)bh * D_ * T_;
  int qr0 = bq * 64 + wave * 16;  // this wave's q-row base
  int r0 = wave * 16;             // staging row base
  int sr = lane >> 3;
  int sc = (((lane & 7) ^ (sr & 7)) * 8);  // XOR-swizzled staging column

  // read-side swizzled chunk offsets (u16 units), constant per lane
  int koff0 = ((quad ^ (lr & 7)) << 3);
  int koff1 = (((4 | quad) ^ (lr & 7)) << 3);

  // Q fragment as MFMA B-operand: B[n=q][k=d] (from global, unswizzled)
  bfrag8 qf[2];
#pragma unroll
  for (int ks = 0; ks < 2; ks++)
    qf[ks] = *(const bfrag8*)(Q + (size_t)(qr0 + lr) * D_ + ks * 32 + quad * 8);

  f32x4 zero = {0.f, 0.f, 0.f, 0.f};
  f32x4 o[4];
#pragma unroll
  for (int nn = 0; nn < 4; nn++) o[nn] = zero;
  float psum = 0.f;

  const u16* gk = Kp + (size_t)(r0 + sr) * D_ + sc;
  const u16* gv = Vp + (size_t)(r0 + sr) * T_ + sc;
  int niter = bq + 1;

  load_lds16(gk, &Ks[0][r0 * 64]);
  load_lds16(gk + (size_t)8 * D_, &Ks[0][(r0 + 8) * 64]);
  load_lds16(gv, &Vt[0][r0 * 64]);
  load_lds16(gv + (size_t)8 * T_, &Vt[0][(r0 + 8) * 64]);

  int buf = 0;
  int qloc = wave * 16 + lr;
  for (int it = 0; it < niter; it++) {
    __syncthreads();  // drains loads for tile `it` (issued one compute-phase ago)
    if (it + 1 < niter) {
      int tkn = (it + 1) * 64;
      load_lds16(gk + (size_t)tkn * D_, &Ks[buf ^ 1][r0 * 64]);
      load_lds16(gk + (size_t)(tkn + 8) * D_, &Ks[buf ^ 1][(r0 + 8) * 64]);
      load_lds16(gv + tkn, &Vt[buf ^ 1][r0 * 64]);
      load_lds16(gv + (size_t)8 * T_ + tkn, &Vt[buf ^ 1][(r0 + 8) * 64]);
    }
    const u16* ks_ = Ks[buf];
    const u16* vt_ = Vt[buf];

    // S^T = K Q^T : 64 kv-rows x 16 q-cols (A=K-frag swizzled, B=Q-frag)
    f32x4 s[4];
#pragma unroll
    for (int j = 0; j < 4; j++) s[j] = zero;
#pragma unroll
    for (int j = 0; j < 4; j++) {
      bfrag8 kf0 = *(const bfrag8*)&ks_[(j * 16 + lr) * 64 + koff0];
      bfrag8 kf1 = *(const bfrag8*)&ks_[(j * 16 + lr) * 64 + koff1];
      s[j] = MFMA_BF16(kf0, qf[0], s[j]);
      s[j] = MFMA_BF16(kf1, qf[1], s[j]);
    }

    // exp + pack pairs (RNE-ish) + ds_write_b64 to Pst[q][t]
    bool edge = (it == bq);  // wave-uniform
#pragma unroll
    for (int j = 0; j < 4; j++) {
      float p[4];
#pragma unroll
      for (int r = 0; r < 4; r++) {
        float e = __expf(s[j][r]);
        if (edge) {
          int kvloc = j * 16 + quad * 4 + r;
          e = (kvloc <= qloc) ? e : 0.f;
        }
        p[r] = e;
        psum += e;
      }
      u32 u0 = __builtin_bit_cast(u32, p[0]) + 0x8000u;
      u32 u1 = __builtin_bit_cast(u32, p[1]) + 0x8000u;
      u32 u2 = __builtin_bit_cast(u32, p[2]) + 0x8000u;
      u32 u3 = __builtin_bit_cast(u32, p[3]) + 0x8000u;
      uint2 pk;
      pk.x = (u0 >> 16) | (u1 & 0xffff0000u);
      pk.y = (u2 >> 16) | (u3 & 0xffff0000u);
      *(uint2*)&Pst[wave][lr * 72 + j * 16 + quad * 4] = pk;
    }

    // O += P V : A = P[q][t] (b128 from Pst), B = V^T[d][t] (swizzled)
#pragma unroll
    for (int ks = 0; ks < 2; ks++) {
      bfrag8 pf = *(const bfrag8*)&Pst[wave][lr * 72 + ks * 32 + quad * 8];
      int ko = ks ? koff1 : koff0;
#pragma unroll
      for (int nn = 0; nn < 4; nn++) {
        bfrag8 vf = *(const bfrag8*)&vt_[(nn * 16 + lr) * 64 + ko];
        o[nn] = MFMA_BF16(pf, vf, o[nn]);
      }
    }
    buf ^= 1;
  }

  // total row-sum: reduce over the 4 quads
  float l = psum;
  l += __shfl_xor(l, 16, 64);
  l += __shfl_xor(l, 32, 64);
  float linv = 1.0f / l;

#pragma unroll
  for (int r = 0; r < 4; r++) {
    float lrec = __shfl(linv, quad * 4 + r, 64);
    int row = qr0 + quad * 4 + r;
#pragma unroll
    for (int nn = 0; nn < 4; nn++)
      ob[(size_t)(b * T_ + row) * C_ + h * 64 + nn * 16 + lr] = f2bf(o[nn][r] * lrec);
  }
}

// -------- GEMM 2: out(f32) = A(4096x1024)bf16 @ WT(1024x1024)bf16 + bias(f32).
// 64x128 tile (grid 512), dbuf LDS, single barrier per iter (round-0 exact). --------
__global__ __launch_bounds__(256) void gemm_proj(const u16* __restrict__ A,
                                                 const u16* __restrict__ WT,
                                                 const float* __restrict__ bias,
                                                 float* __restrict__ out) {
  const int K = C_;
  __shared__ __align__(16) u16 As[2][64 * 32];
  __shared__ __align__(16) u16 Bs[2][128 * 32];
  int tid = threadIdx.x;
  int lane = tid & 63, wave = tid >> 6;
  int quad = lane >> 4, lr = lane & 15;
  int m0 = blockIdx.y * 64, n0 = blockIdx.x * 128;
  int wcol = wave * 32;
  int srow = lane >> 2, skc = (lane & 3) * 8;

  f32x4 zero = {0.f, 0.f, 0.f, 0.f};
  f32x4 acc[4][2];
#pragma unroll
  for (int i = 0; i < 4; i++)
#pragma unroll
    for (int j = 0; j < 2; j++) acc[i][j] = zero;

  const u16* ga = A + (size_t)(m0 + wave * 16 + srow) * K + skc;
  const u16* gb0 = WT + (size_t)(n0 + wave * 32 + srow) * K + skc;
  const u16* gb1 = WT + (size_t)(n0 + wave * 32 + 16 + srow) * K + skc;

  load_lds16(ga, &As[0][wave * 16 * 32]);
  load_lds16(gb0, &Bs[0][wave * 32 * 32]);
  load_lds16(gb1, &Bs[0][(wave * 32 + 16) * 32]);

  int buf = 0;
  for (int k0 = 0; k0 < K; k0 += 32) {
    __syncthreads();
    if (k0 + 32 < K) {
      load_lds16(ga + k0 + 32, &As[buf ^ 1][wave * 16 * 32]);
      load_lds16(gb0 + k0 + 32, &Bs[buf ^ 1][wave * 32 * 32]);
      load_lds16(gb1 + k0 + 32, &Bs[buf ^ 1][(wave * 32 + 16) * 32]);
    }
    bfrag8 af[4], bfr[2];
#pragma unroll
    for (int i = 0; i < 4; i++)
      af[i] = *(const bfrag8*)&As[buf][(i * 16 + lr) * 32 + quad * 8];
#pragma unroll
    for (int j = 0; j < 2; j++)
      bfr[j] = *(const bfrag8*)&Bs[buf][(wcol + j * 16 + lr) * 32 + quad * 8];
#pragma unroll
    for (int i = 0; i < 4; i++)
#pragma unroll
      for (int j = 0; j < 2; j++) acc[i][j] = MFMA_BF16(af[i], bfr[j], acc[i][j]);
    buf ^= 1;
  }

#pragma unroll
  for (int i = 0; i < 4; i++)
#pragma unroll
    for (int r = 0; r < 4; r++) {
      int m = m0 + i * 16 + quad * 4 + r;
#pragma unroll
      for (int j = 0; j < 2; j++) {
        int n = n0 + wcol + j * 16 + lr;
        out[(size_t)m * C_ + n] = acc[i][j][r] + bias[n];
      }
    }
}

extern "C" void kernel_launch(void* const* d_in, const int* in_sizes, int n_in,
                              void* d_out, int out_size, void* d_ws, size_t ws_size,
                              hipStream_t stream) {
  const float* x = (const float*)d_in[0];       // [4096,1024] f32
  const float* w_qkv = (const float*)d_in[1];   // [1024,3072] f32
  const float* w_proj = (const float*)d_in[2];  // [1024,1024] f32
  const float* b_proj = (const float*)d_in[3];  // [1024] f32

  char* w = (char*)d_ws;
  u16* xb = (u16*)(w + 256);                 // 4096*1024 bf16
  u16* vtb = xb;                             // alias: used after xb is dead
  u16* regA = xb + (size_t)4096 * 1024;      // max(wqkvT, abuf)
  u16* wqkvT = regA;                         // 3072*1024 (dead after gemm_qkv)
  u16* abuf = regA;                          // 4096*1024 (written by attn)
  u16* wprojT = regA + (size_t)4096 * 1024;  // 1024*1024
  u16* qbuf = wprojT + (size_t)1024 * 1024;
  u16* kbuf = qbuf + (size_t)B_ * H_ * T_ * D_;
  u16* vbuf = kbuf + (size_t)B_ * H_ * T_ * D_;

  convert_x<<<2048, 256, 0, stream>>>(x, xb);
  transpose_w<<<dim3(NQKV_ / 64, C_ / 64), 256, 0, stream>>>(w_qkv, wqkvT, C_, NQKV_);
  transpose_w<<<dim3(C_ / 64, C_ / 64), 256, 0, stream>>>(w_proj, wprojT, C_, C_);
  gemm_qkv_rope<<<dim3(NQKV_ / 128, (B_ * T_) / 128), 256, 0, stream>>>(xb, wqkvT, qbuf, kbuf, vbuf);
  transpose_v<<<dim3(T_ / 64, B_ * H_), 256, 0, stream>>>(vbuf, vtb);
  attn_k<<<1024, 256, 0, stream>>>(qbuf, kbuf, vtb, abuf);
  gemm_proj<<<dim3(C_ / 128, (B_ * T_) / 64), 256, 0, stream>>>(abuf, wprojT, b_proj, (float*)d_out);
}